// Round 7
// baseline (321.140 us; speedup 1.0000x reference)
//
#include <hip/hip_runtime.h>
#include <hip/hip_bf16.h>

// MoE block: x[8192,1024] @ w1w3[E,1024,2816] -> swiglu -> h[8192,1408]
//            @ w2[E,1408,1024] -> out[8192,1024]. fp32 inputs (autodetected;
//            bf16 handled too).
// R12 (this round): gemm2 retile 128x128 -> 128x64 (exact copy of gemm1's
//   proven GEMM geometry: 4x2 acc, 1 B-gload/wave, 24KB LDS -> 6 blocks/CU).
//   R11 showed gemm2 at 576 blocks = 2.25/CU (vs gemm1's 8.9 offered) --
//   under-occupied for the latency-hiding this 2-barrier structure relies on.
//   Grid 16x72=1152 (4.5/CU), T1 swizzle 1152=8*144.
//   Everything else byte-identical to R11 (313.6us best: gemm1 85us,
//   FETCH 103MB near-ideal, conflicts 0).

#define HIDDEN 1024
#define INTER  1408
#define NEXP   8
#define TOKENS 8192

typedef __attribute__((ext_vector_type(8))) short bf16x8;
typedef __attribute__((ext_vector_type(4))) float f32x4;
typedef __attribute__((ext_vector_type(4))) unsigned short u16x4;
typedef __attribute__((ext_vector_type(8))) unsigned short u16x8;

#define GLOAD_LDS16(g, l)                                                      \
  __builtin_amdgcn_global_load_lds(                                            \
      (const __attribute__((address_space(1))) void*)(g),                      \
      (__attribute__((address_space(3))) void*)(l), 16, 0, 0)

__device__ inline unsigned short f2bf(float f) {
  unsigned int x = __float_as_uint(f);
  x += 0x7fffu + ((x >> 16) & 1u);   // RNE
  return (unsigned short)(x >> 16);
}

// Wave-uniform fp32-vs-bf16 detection from x[0..63] viewed as fp32.
__device__ inline int detect_f32(const float* __restrict__ xf, int lane) {
  unsigned int u = __float_as_uint(xf[lane & 63]);
  int e = (u >> 23) & 0xff;
  return __popcll(__ballot(e >= 100 && e <= 140)) >= 48 ? 1 : 0;
}

// ---------- tokens_per_expert parsing (int32 / int64-lo / fallback) ----------
__device__ inline void load_tpe(const int* __restrict__ raw, int* tpe) {
  bool ok = true; int s = 0;
#pragma unroll
  for (int e = 0; e < NEXP; e++) { int v = raw[e]; tpe[e] = v; ok = ok && (v >= 0 && v <= TOKENS); s += v; }
  if (ok && s == TOKENS) return;
  ok = true; s = 0;
#pragma unroll
  for (int e = 0; e < NEXP; e++) { int v = raw[2 * e]; tpe[e] = v; ok = ok && (v >= 0 && v <= TOKENS); s += v; }
  if (ok && s == TOKENS) return;
  const int fb[NEXP] = {700, 1300, 900, 1100, 1024, 1024, 800, 1344};
#pragma unroll
  for (int e = 0; e < NEXP; e++) tpe[e] = fb[e];
}

__device__ inline bool expert_map(const int* __restrict__ tpe_raw, int rt,
                                  int& expert, int& row0, int& rows_valid) {
  int tpe[NEXP];
  load_tpe(tpe_raw, tpe);
  int acc = 0, pre = 0;
#pragma unroll
  for (int e = 0; e < NEXP; e++) {
    int nt = (tpe[e] + 127) >> 7;
    if (rt < acc + nt) {
      int ti = rt - acc;
      expert = e; row0 = pre + ti * 128; rows_valid = tpe[e] - ti * 128;
      return true;
    }
    acc += nt; pre += tpe[e];
  }
  return false;
}

// ---------- LDS-staged transpose: in[R][C] -> out[C][R] bf16 ----------
// Tile RE(r) x CE(c), THREADS threads, LDS = CE*NRCH*16B.
// chunk address = c*NRCH + (rch ^ ((c>>2)&MASK)) -> balanced banks, 16B ops.
// Phase 1: lanes column-major -> global reads 512B segments.
// Phase 2: lanes row-major -> global writes RE*2 B segments.
template <int THREADS, int RE, int CE, int LOG_NC4, int LOG_NRCH>
__device__ inline void ldst_transpose(const void* __restrict__ in,
                                      unsigned short* __restrict__ out,
                                      int R, int C, int r0, int c0,
                                      int t, int f32,
                                      unsigned short* __restrict__ lds) {
  constexpr int NC4 = 1 << LOG_NC4;     // CE/4 column chunks
  constexpr int NRCH = 1 << LOG_NRCH;   // RE/8 row chunks
  constexpr int MASK = NRCH - 1;
  constexpr int RPR = (THREADS >> LOG_NC4) * 8;   // rows per round
  constexpr int ROUNDS = RE / RPR;
  static_assert(NC4 * 4 == CE && NRCH * 8 == RE, "geometry");
  static_assert(ROUNDS * RPR == RE, "rounds");

  const int clane = t & (NC4 - 1);
  const int rslot = t >> LOG_NC4;
  const int c = clane * 4;              // tile-local col (x4 per load)
#pragma unroll
  for (int round = 0; round < ROUNDS; ++round) {
    const int rb = round * RPR + rslot * 8;     // tile-local row base
    u16x8 w[4];
    if (f32) {
      f32x4 v[8];
#pragma unroll
      for (int i = 0; i < 8; i++)
        v[i] = *(const f32x4*)((const float*)in + (size_t)(r0 + rb + i) * C + c0 + c);
#pragma unroll
      for (int j = 0; j < 4; j++)
#pragma unroll
        for (int i = 0; i < 8; i++) w[j][i] = f2bf(v[i][j]);
    } else {
      u16x4 v[8];
#pragma unroll
      for (int i = 0; i < 8; i++)
        v[i] = *(const u16x4*)((const unsigned short*)in + (size_t)(r0 + rb + i) * C + c0 + c);
#pragma unroll
      for (int j = 0; j < 4; j++)
#pragma unroll
        for (int i = 0; i < 8; i++) w[j][i] = v[i][j];
    }
    const int rch = rb >> 3;
#pragma unroll
    for (int j = 0; j < 4; j++) {
      const int cc = c + j;
      const int chunk = (cc << LOG_NRCH) + (rch ^ ((cc >> 2) & MASK));
      *(u16x8*)&lds[chunk * 8] = w[j];
    }
  }
  __syncthreads();

  const int rl = t & (NRCH - 1);
  const int cslot = t >> LOG_NRCH;
  constexpr int CSLOTS = THREADS >> LOG_NRCH;
#pragma unroll
  for (int it = 0; it < CE / CSLOTS; ++it) {
    const int crow = it * CSLOTS + cslot;
    const int chunk = (crow << LOG_NRCH) + (rl ^ ((crow >> 2) & MASK));
    u16x8 w = *(const u16x8*)&lds[chunk * 8];
    *(u16x8*)&out[(size_t)(c0 + crow) * R + r0 + rl * 8] = w;
  }
}

// ---------- prepare: x conversion + w1 transpose (512 threads) ----------
//   [0, 256):     x -> xb bf16 (32768 elems/block)
//   [256, 960):   w1w3 [e][1024][2816] -> w1t [e][2816][1024]
//                 tile 256r x 128c, 64KB LDS: 8 x (4 rt x 22 ct) = 704 blocks
__global__ __launch_bounds__(512) void prepare(
    const float* __restrict__ xf, const void* __restrict__ x,
    const void* __restrict__ w1w3,
    unsigned short* __restrict__ xb, unsigned short* __restrict__ w1t) {
  __shared__ __align__(16) unsigned short lds[32768];   // 64 KB
  const int t = threadIdx.x;
  const int f32 = detect_f32(xf, t & 63);
  const int b = blockIdx.x;

  if (b < 256) {
    const size_t base = (size_t)b * 32768 + t * 4;
#pragma unroll
    for (int it = 0; it < 16; ++it) {
      const size_t i = base + (size_t)it * 2048;
      u16x4 v;
      if (f32) {
        f32x4 g = *(const f32x4*)((const float*)x + i);
        v[0] = f2bf(g[0]); v[1] = f2bf(g[1]); v[2] = f2bf(g[2]); v[3] = f2bf(g[3]);
      } else {
        v = *(const u16x4*)((const unsigned short*)x + i);
      }
      *(u16x4*)(xb + i) = v;
    }
    return;
  }

  const int u = b - 256;               // 8 experts x (4 rt x 22 ct)
  const int ex = u / 88, rem = u % 88;
  const int r0 = (rem / 22) * 256, c0 = (rem % 22) * 128;
  const char* in = (const char*)w1w3 + (size_t)ex * 1024 * 2816 * (f32 ? 4 : 2);
  ldst_transpose<512, 256, 128, 5, 5>(in, w1t + (size_t)ex * 2816 * 1024,
                                      1024, 2816, r0, c0, t, f32, lds);
}

// ---------- GEMM1 (+ fused w2 transpose role): tile 128M x 64N fused --------
// by in [0,72): h = silu(x@Wg) * (x@Wu). w1t [E][2816][1024] N-major.
// by in [72,104): w2 [e][1408][1024] -> w2t [e][1024][1408] (704 tiles).
// T1 split domains: GEMM ids (0..1583 = 8*198) and transpose ids
// (1584..2287 = 8*88) swizzled independently -> every XCD gets 9 GEMM
// y-rows (A-panel L2 reuse) + 88 transposes.
__global__ __launch_bounds__(256, 2) void moe_gemm1(
    const unsigned short* __restrict__ xb, const unsigned short* __restrict__ w1t,
    const int* __restrict__ tpe_raw, unsigned short* __restrict__ h,
    const void* __restrict__ w2raw, unsigned short* __restrict__ w2t,
    const float* __restrict__ xf) {
  __shared__ __align__(16) unsigned short smem[16384];  // 32 KB union
  const int tid = threadIdx.x;

  const int lin = blockIdx.y * 22 + blockIdx.x;         // nwg = 2288
  int swz;
  if (lin < 1584) {                                     // 1584 = 8*198 GEMM
    swz = (lin & 7) * 198 + (lin >> 3);
  } else {                                              // 704 = 8*88 transpose
    const int tt = lin - 1584;
    swz = 1584 + (tt & 7) * 88 + (tt >> 3);
  }
  const int by = swz / 22, bx = swz % 22;

  if (by >= 72) {   // ---- w2 transpose role ----
    const int f32 = detect_f32(xf, tid & 63);
    const int idx = (by - 72) * 22 + bx;                // 0..703
    const int ex = idx / 88, rem = idx % 88;
    const int r0 = (rem / 8) * 128, c0 = (rem % 8) * 128;
    const char* in = (const char*)w2raw + (size_t)ex * 1408 * 1024 * (f32 ? 4 : 2);
    ldst_transpose<256, 128, 128, 5, 4>(in, w2t + (size_t)ex * 1024 * 1408,
                                        1408, 1024, r0, c0, tid, f32, smem);
    return;
  }

  // ---- GEMM role (byte-identical to R8/R11's proven body) ----
  // smem: As[2][4096] | Bg[2][2048] | Bu[2][2048]  (32 KB)
#define AS(b_) (smem + (b_) * 4096)
#define BG(b_) (smem + 8192 + (b_) * 2048)
#define BU(b_) (smem + 12288 + (b_) * 2048)
  int expert, row0, rows_valid;
  if (!expert_map(tpe_raw, by, expert, row0, rows_valid)) return;

  const int lane = tid & 63, wave = tid >> 6;
  const int wr = wave >> 1, wc = wave & 1;
  const int i0 = bx * 64;
  const unsigned short* W = w1t + (size_t)expert * 2816 * HIDDEN;

  const int q0 = wave * 2, q1 = wave * 2 + 1;
  const int sr0 = q0 * 16 + (lane >> 2), sr1 = q1 * 16 + (lane >> 2);
  const int sb = wave * 16 + (lane >> 2);
  // T2 pre-swizzled source chunk (write side of the LDS swizzle).
  const int sk = (((lane & 3) ^ ((lane >> 3) & 3))) * 8;
  const size_t arow0 = (size_t)min(row0 + sr0, TOKENS - 1);
  const size_t arow1 = (size_t)min(row0 + sr1, TOKENS - 1);
  const unsigned short* pa0 = xb + arow0 * HIDDEN + sk;
  const unsigned short* pa1 = xb + arow1 * HIDDEN + sk;
  const unsigned short* pg = W + (size_t)(i0 + sb) * HIDDEN + sk;
  const unsigned short* pu = W + (size_t)(INTER + i0 + sb) * HIDDEN + sk;

  f32x4 accg[4][2] = {};
  f32x4 accu[4][2] = {};
  const int fr = lane & 15, fq = (lane >> 4) * 8;
  const int fqs = fq ^ (((fr >> 1) & 3) << 3);   // T2 read-side (lane const)

  // prologue: stage K-tile 0 into buffer 0
  GLOAD_LDS16(pa0, AS(0) + q0 * 512);
  GLOAD_LDS16(pa1, AS(0) + q1 * 512);
  GLOAD_LDS16(pg, BG(0) + wave * 512);
  GLOAD_LDS16(pu, BU(0) + wave * 512);
  pa0 += 32; pa1 += 32; pg += 32; pu += 32;
  __syncthreads();

  const int NT = HIDDEN / 32;   // 32
  for (int it = 0; it < NT; ++it) {
    const int cur = it & 1, nxt = cur ^ 1;
    if (it + 1 < NT) {
      GLOAD_LDS16(pa0, AS(nxt) + q0 * 512);
      GLOAD_LDS16(pa1, AS(nxt) + q1 * 512);
      GLOAD_LDS16(pg, BG(nxt) + wave * 512);
      GLOAD_LDS16(pu, BU(nxt) + wave * 512);
      pa0 += 32; pa1 += 32; pg += 32; pu += 32;
    }

    bf16x8 a[4], bg[2], bu[2];
#pragma unroll
    for (int mi = 0; mi < 4; mi++)
      a[mi] = *(const bf16x8*)&AS(cur)[(wr * 64 + mi * 16 + fr) * 32 + fqs];
#pragma unroll
    for (int ni = 0; ni < 2; ni++) {
      bg[ni] = *(const bf16x8*)&BG(cur)[(wc * 32 + ni * 16 + fr) * 32 + fqs];
      bu[ni] = *(const bf16x8*)&BU(cur)[(wc * 32 + ni * 16 + fr) * 32 + fqs];
    }
#pragma unroll
    for (int mi = 0; mi < 4; mi++)
#pragma unroll
      for (int ni = 0; ni < 2; ni++) {
        accg[mi][ni] =
            __builtin_amdgcn_mfma_f32_16x16x32_bf16(a[mi], bg[ni], accg[mi][ni], 0, 0, 0);
        accu[mi][ni] =
            __builtin_amdgcn_mfma_f32_16x16x32_bf16(a[mi], bu[ni], accu[mi][ni], 0, 0, 0);
      }

    __syncthreads();
  }

  // C/D layout: col=lane&15, row=(lane>>4)*4+r  [measured m89/m91]
#pragma unroll
  for (int mi = 0; mi < 4; mi++)
#pragma unroll
    for (int r = 0; r < 4; r++) {
      const int row_local = wr * 64 + mi * 16 + ((lane >> 4) * 4) + r;
      if (row_local < rows_valid && row0 + row_local < TOKENS) {
        const size_t rowoff = (size_t)(row0 + row_local) * INTER;
#pragma unroll
        for (int ni = 0; ni < 2; ni++) {
          const int col = i0 + wc * 32 + ni * 16 + fr;
          const float g = accg[mi][ni][r];
          const float u = accu[mi][ni][r];
          const float sg = g / (1.0f + __expf(-g));
          h[rowoff + col] = f2bf(sg * u);
        }
      }
    }
#undef AS
#undef BG
#undef BU
}

// ---------- GEMM2: out = h @ w2[e], tile 128M x 64N (gemm1 geometry) --------
// R12: retiled from 128x128/576 blocks (2.25/CU, under-occupied) to the
// proven gemm1 geometry: 4x2 acc, 1 B-gload/wave, 24KB LDS (6 blocks/CU cap),
// grid 16x72 = 1152 blocks (4.5/CU). T1 swizzle 1152 = 8*144.
__global__ __launch_bounds__(256, 2) void moe_gemm2(
    const unsigned short* __restrict__ h, const unsigned short* __restrict__ w2t,
    const int* __restrict__ tpe_raw, void* __restrict__ out,
    const float* __restrict__ xf) {
  __shared__ __align__(16) unsigned short As[2][4096];   // 16 KB
  __shared__ __align__(16) unsigned short Bs[2][2048];   //  8 KB

  // T1: bijective XCD chunk swizzle. nwg = 1152 = 8*144 (9 y-rows per XCD).
  const int lin = blockIdx.y * 16 + blockIdx.x;
  const int swz = (lin & 7) * 144 + (lin >> 3);
  const int by = swz >> 4, bx = swz & 15;

  int expert, row0, rows_valid;
  if (!expert_map(tpe_raw, by, expert, row0, rows_valid)) return;
  const int f32out = detect_f32(xf, threadIdx.x & 63);

  const int tid = threadIdx.x;
  const int lane = tid & 63, wave = tid >> 6;
  const int wr = wave >> 1, wc = wave & 1;
  const int n0 = bx * 64;
  const unsigned short* W = w2t + (size_t)expert * INTER * HIDDEN;

  const int q0 = wave * 2, q1 = wave * 2 + 1;
  const int sr0 = q0 * 16 + (lane >> 2), sr1 = q1 * 16 + (lane >> 2);
  const int sb = wave * 16 + (lane >> 2);
  const int sk = (((lane & 3) ^ ((lane >> 3) & 3))) * 8;   // T2 source swizzle
  const size_t arow0 = (size_t)min(row0 + sr0, TOKENS - 1);
  const size_t arow1 = (size_t)min(row0 + sr1, TOKENS - 1);
  const unsigned short* pa0 = h + arow0 * INTER + sk;
  const unsigned short* pa1 = h + arow1 * INTER + sk;
  const unsigned short* pb = W + (size_t)(n0 + sb) * INTER + sk;

  f32x4 acc[4][2] = {};
  const int fr = lane & 15, fq = (lane >> 4) * 8;
  const int fqs = fq ^ (((fr >> 1) & 3) << 3);             // T2 read swizzle

  // prologue: stage K-tile 0
  GLOAD_LDS16(pa0, &As[0][q0 * 512]);
  GLOAD_LDS16(pa1, &As[0][q1 * 512]);
  GLOAD_LDS16(pb, &Bs[0][wave * 512]);
  pa0 += 32; pa1 += 32; pb += 32;
  __syncthreads();

  const int NT = INTER / 32;   // 44
  for (int it = 0; it < NT; ++it) {
    const int cur = it & 1, nxt = cur ^ 1;
    if (it + 1 < NT) {
      GLOAD_LDS16(pa0, &As[nxt][q0 * 512]);
      GLOAD_LDS16(pa1, &As[nxt][q1 * 512]);
      GLOAD_LDS16(pb, &Bs[nxt][wave * 512]);
      pa0 += 32; pa1 += 32; pb += 32;
    }

    bf16x8 a[4], bb[2];
#pragma unroll
    for (int mi = 0; mi < 4; mi++)
      a[mi] = *(const bf16x8*)&As[cur][(wr * 64 + mi * 16 + fr) * 32 + fqs];
#pragma unroll
    for (int ni = 0; ni < 2; ni++)
      bb[ni] = *(const bf16x8*)&Bs[cur][(wc * 32 + ni * 16 + fr) * 32 + fqs];
#pragma unroll
    for (int mi = 0; mi < 4; mi++)
#pragma unroll
      for (int ni = 0; ni < 2; ni++)
        acc[mi][ni] =
            __builtin_amdgcn_mfma_f32_16x16x32_bf16(a[mi], bb[ni], acc[mi][ni], 0, 0, 0);

    __syncthreads();
  }

#pragma unroll
  for (int mi = 0; mi < 4; mi++)
#pragma unroll
    for (int r = 0; r < 4; r++) {
      const int row_local = wr * 64 + mi * 16 + ((lane >> 4) * 4) + r;
      if (row_local < rows_valid && row0 + row_local < TOKENS) {
        const size_t rowoff = (size_t)(row0 + row_local) * HIDDEN;
#pragma unroll
        for (int ni = 0; ni < 2; ni++) {
          const int col = n0 + wc * 32 + ni * 16 + fr;
          if (f32out)
            ((float*)out)[rowoff + col] = acc[mi][ni][r];
          else
            ((unsigned short*)out)[rowoff + col] = f2bf(acc[mi][ni][r]);
        }
      }
    }
}

extern "C" void kernel_launch(void* const* d_in, const int* in_sizes, int n_in,
                              void* d_out, int out_size, void* d_ws, size_t ws_size,
                              hipStream_t stream) {
  const void* x = d_in[0];
  const void* w1w3 = d_in[1];
  const void* w2 = d_in[2];
  const int* tpe = (const int*)d_in[3];
  const float* xf = (const float*)d_in[0];

  // ws: xb[8192][1024] | w1t[8][2816][1024] | w2t[8][1024][1408] | h[8192][1408]
  const size_t XB_BYTES = (size_t)TOKENS * HIDDEN * 2;         // 16,777,216
  const size_t W1T_BYTES = (size_t)NEXP * 2816 * HIDDEN * 2;   // 46,137,344
  const size_t W2T_BYTES = (size_t)NEXP * INTER * HIDDEN * 2;  // 23,068,672
  char* ws = (char*)d_ws;
  unsigned short* xb = (unsigned short*)ws;
  unsigned short* w1t = (unsigned short*)(ws + XB_BYTES);
  unsigned short* w2t = (unsigned short*)(ws + XB_BYTES + W1T_BYTES);
  unsigned short* h = (unsigned short*)(ws + XB_BYTES + W1T_BYTES + W2T_BYTES);

  prepare<<<960, 512, 0, stream>>>(xf, x, w1w3, xb, w1t);
  // gemm1 grid: y in [0,72) = GEMM tiles; y in [72,104) = w2-transpose blocks
  moe_gemm1<<<dim3(22, 104), 256, 0, stream>>>(xb, w1t, tpe, h, w2, w2t, xf);
  moe_gemm2<<<dim3(16, 72), 256, 0, stream>>>(h, w2t, tpe, d_out, xf);
}

// Round 8
// 312.012 us; speedup vs baseline: 1.0293x; 1.0293x over previous
//
#include <hip/hip_runtime.h>
#include <hip/hip_bf16.h>

// MoE block: x[8192,1024] @ w1w3[E,1024,2816] -> swiglu -> h[8192,1408]
//            @ w2[E,1408,1024] -> out[8192,1024]. fp32 inputs (autodetected;
//            bf16 handled too).
// R13 (this round): R11 base (best measured 313.6us) with gemm2 reverted to
//   128x128 (R12's 128x64 retile unresolvable: identical gemm1 code drifted
//   +9% across runs). ONE isolated change: prepare w1-transpose tile
//   256r x 128c @512t/64KB (2 blocks/CU, latency-bound) -> 256r x 64c
//   @256t/32KB (5 blocks/CU, 1408 blocks). Write segments stay 512B
//   (NRCH=32); read segments 256B. Bank audit: ph1 2 lanes/bank (free),
//   ph2 1 lane/bank. x-conv back to R8's proven 512-block form.

#define HIDDEN 1024
#define INTER  1408
#define NEXP   8
#define TOKENS 8192

typedef __attribute__((ext_vector_type(8))) short bf16x8;
typedef __attribute__((ext_vector_type(4))) float f32x4;
typedef __attribute__((ext_vector_type(4))) unsigned short u16x4;
typedef __attribute__((ext_vector_type(8))) unsigned short u16x8;

#define GLOAD_LDS16(g, l)                                                      \
  __builtin_amdgcn_global_load_lds(                                            \
      (const __attribute__((address_space(1))) void*)(g),                      \
      (__attribute__((address_space(3))) void*)(l), 16, 0, 0)

__device__ inline unsigned short f2bf(float f) {
  unsigned int x = __float_as_uint(f);
  x += 0x7fffu + ((x >> 16) & 1u);   // RNE
  return (unsigned short)(x >> 16);
}

// Wave-uniform fp32-vs-bf16 detection from x[0..63] viewed as fp32.
__device__ inline int detect_f32(const float* __restrict__ xf, int lane) {
  unsigned int u = __float_as_uint(xf[lane & 63]);
  int e = (u >> 23) & 0xff;
  return __popcll(__ballot(e >= 100 && e <= 140)) >= 48 ? 1 : 0;
}

// ---------- tokens_per_expert parsing (int32 / int64-lo / fallback) ----------
__device__ inline void load_tpe(const int* __restrict__ raw, int* tpe) {
  bool ok = true; int s = 0;
#pragma unroll
  for (int e = 0; e < NEXP; e++) { int v = raw[e]; tpe[e] = v; ok = ok && (v >= 0 && v <= TOKENS); s += v; }
  if (ok && s == TOKENS) return;
  ok = true; s = 0;
#pragma unroll
  for (int e = 0; e < NEXP; e++) { int v = raw[2 * e]; tpe[e] = v; ok = ok && (v >= 0 && v <= TOKENS); s += v; }
  if (ok && s == TOKENS) return;
  const int fb[NEXP] = {700, 1300, 900, 1100, 1024, 1024, 800, 1344};
#pragma unroll
  for (int e = 0; e < NEXP; e++) tpe[e] = fb[e];
}

__device__ inline bool expert_map(const int* __restrict__ tpe_raw, int rt,
                                  int& expert, int& row0, int& rows_valid) {
  int tpe[NEXP];
  load_tpe(tpe_raw, tpe);
  int acc = 0, pre = 0;
#pragma unroll
  for (int e = 0; e < NEXP; e++) {
    int nt = (tpe[e] + 127) >> 7;
    if (rt < acc + nt) {
      int ti = rt - acc;
      expert = e; row0 = pre + ti * 128; rows_valid = tpe[e] - ti * 128;
      return true;
    }
    acc += nt; pre += tpe[e];
  }
  return false;
}

// ---------- LDS-staged transpose: in[R][C] -> out[C][R] bf16 ----------
// Tile RE(r) x CE(c), THREADS threads, LDS = CE*NRCH*16B.
// chunk address = c*NRCH + (rch ^ ((c>>2)&MASK)) -> balanced banks, 16B ops.
// Phase 1: lanes column-major -> global reads NC4*16 B segments.
// Phase 2: lanes row-major -> global writes NRCH*16 B segments.
template <int THREADS, int RE, int CE, int LOG_NC4, int LOG_NRCH>
__device__ inline void ldst_transpose(const void* __restrict__ in,
                                      unsigned short* __restrict__ out,
                                      int R, int C, int r0, int c0,
                                      int t, int f32,
                                      unsigned short* __restrict__ lds) {
  constexpr int NC4 = 1 << LOG_NC4;     // CE/4 column chunks
  constexpr int NRCH = 1 << LOG_NRCH;   // RE/8 row chunks
  constexpr int MASK = NRCH - 1;
  constexpr int RPR = (THREADS >> LOG_NC4) * 8;   // rows per round
  constexpr int ROUNDS = RE / RPR;
  static_assert(NC4 * 4 == CE && NRCH * 8 == RE, "geometry");
  static_assert(ROUNDS * RPR == RE, "rounds");

  const int clane = t & (NC4 - 1);
  const int rslot = t >> LOG_NC4;
  const int c = clane * 4;              // tile-local col (x4 per load)
#pragma unroll
  for (int round = 0; round < ROUNDS; ++round) {
    const int rb = round * RPR + rslot * 8;     // tile-local row base
    u16x8 w[4];
    if (f32) {
      f32x4 v[8];
#pragma unroll
      for (int i = 0; i < 8; i++)
        v[i] = *(const f32x4*)((const float*)in + (size_t)(r0 + rb + i) * C + c0 + c);
#pragma unroll
      for (int j = 0; j < 4; j++)
#pragma unroll
        for (int i = 0; i < 8; i++) w[j][i] = f2bf(v[i][j]);
    } else {
      u16x4 v[8];
#pragma unroll
      for (int i = 0; i < 8; i++)
        v[i] = *(const u16x4*)((const unsigned short*)in + (size_t)(r0 + rb + i) * C + c0 + c);
#pragma unroll
      for (int j = 0; j < 4; j++)
#pragma unroll
        for (int i = 0; i < 8; i++) w[j][i] = v[i][j];
    }
    const int rch = rb >> 3;
#pragma unroll
    for (int j = 0; j < 4; j++) {
      const int cc = c + j;
      const int chunk = (cc << LOG_NRCH) + (rch ^ ((cc >> 2) & MASK));
      *(u16x8*)&lds[chunk * 8] = w[j];
    }
  }
  __syncthreads();

  const int rl = t & (NRCH - 1);
  const int cslot = t >> LOG_NRCH;
  constexpr int CSLOTS = THREADS >> LOG_NRCH;
#pragma unroll
  for (int it = 0; it < CE / CSLOTS; ++it) {
    const int crow = it * CSLOTS + cslot;
    const int chunk = (crow << LOG_NRCH) + (rl ^ ((crow >> 2) & MASK));
    u16x8 w = *(const u16x8*)&lds[chunk * 8];
    *(u16x8*)&out[(size_t)(c0 + crow) * R + r0 + rl * 8] = w;
  }
}

// ---------- prepare: x conversion + w1 transpose (256 threads) ----------
//   [0, 512):      x -> xb bf16 (16384 elems/block)
//   [512, 1920):   w1w3 [e][1024][2816] -> w1t [e][2816][1024]
//                  tile 256r x 64c, 32KB LDS: 8 x (4 rt x 44 ct) = 1408 blocks
__global__ __launch_bounds__(256) void prepare(
    const float* __restrict__ xf, const void* __restrict__ x,
    const void* __restrict__ w1w3,
    unsigned short* __restrict__ xb, unsigned short* __restrict__ w1t) {
  __shared__ __align__(16) unsigned short lds[16384];   // 32 KB
  const int t = threadIdx.x;
  const int f32 = detect_f32(xf, t & 63);
  const int b = blockIdx.x;

  if (b < 512) {
    const size_t base = (size_t)b * 16384 + t * 4;
#pragma unroll
    for (int it = 0; it < 16; ++it) {
      const size_t i = base + (size_t)it * 1024;
      u16x4 v;
      if (f32) {
        f32x4 g = *(const f32x4*)((const float*)x + i);
        v[0] = f2bf(g[0]); v[1] = f2bf(g[1]); v[2] = f2bf(g[2]); v[3] = f2bf(g[3]);
      } else {
        v = *(const u16x4*)((const unsigned short*)x + i);
      }
      *(u16x4*)(xb + i) = v;
    }
    return;
  }

  const int u = b - 512;               // 8 experts x (4 rt x 44 ct)
  const int ex = u / 176, rem = u % 176;
  const int r0 = (rem / 44) * 256, c0 = (rem % 44) * 64;
  const char* in = (const char*)w1w3 + (size_t)ex * 1024 * 2816 * (f32 ? 4 : 2);
  ldst_transpose<256, 256, 64, 4, 5>(in, w1t + (size_t)ex * 2816 * 1024,
                                     1024, 2816, r0, c0, t, f32, lds);
}

// ---------- GEMM1 (+ fused w2 transpose role): tile 128M x 64N fused --------
// by in [0,72): h = silu(x@Wg) * (x@Wu). w1t [E][2816][1024] N-major.
// by in [72,104): w2 [e][1408][1024] -> w2t [e][1024][1408] (704 tiles).
// T1 split domains: GEMM ids (0..1583 = 8*198) and transpose ids
// (1584..2287 = 8*88) swizzled independently -> every XCD gets 9 GEMM
// y-rows (A-panel L2 reuse) + 88 transposes.
__global__ __launch_bounds__(256, 2) void moe_gemm1(
    const unsigned short* __restrict__ xb, const unsigned short* __restrict__ w1t,
    const int* __restrict__ tpe_raw, unsigned short* __restrict__ h,
    const void* __restrict__ w2raw, unsigned short* __restrict__ w2t,
    const float* __restrict__ xf) {
  __shared__ __align__(16) unsigned short smem[16384];  // 32 KB union
  const int tid = threadIdx.x;

  const int lin = blockIdx.y * 22 + blockIdx.x;         // nwg = 2288
  int swz;
  if (lin < 1584) {                                     // 1584 = 8*198 GEMM
    swz = (lin & 7) * 198 + (lin >> 3);
  } else {                                              // 704 = 8*88 transpose
    const int tt = lin - 1584;
    swz = 1584 + (tt & 7) * 88 + (tt >> 3);
  }
  const int by = swz / 22, bx = swz % 22;

  if (by >= 72) {   // ---- w2 transpose role ----
    const int f32 = detect_f32(xf, tid & 63);
    const int idx = (by - 72) * 22 + bx;                // 0..703
    const int ex = idx / 88, rem = idx % 88;
    const int r0 = (rem / 8) * 128, c0 = (rem % 8) * 128;
    const char* in = (const char*)w2raw + (size_t)ex * 1408 * 1024 * (f32 ? 4 : 2);
    ldst_transpose<256, 128, 128, 5, 4>(in, w2t + (size_t)ex * 1024 * 1408,
                                        1408, 1024, r0, c0, tid, f32, smem);
    return;
  }

  // ---- GEMM role (byte-identical to R8/R11's proven body) ----
  // smem: As[2][4096] | Bg[2][2048] | Bu[2][2048]  (32 KB)
#define AS(b_) (smem + (b_) * 4096)
#define BG(b_) (smem + 8192 + (b_) * 2048)
#define BU(b_) (smem + 12288 + (b_) * 2048)
  int expert, row0, rows_valid;
  if (!expert_map(tpe_raw, by, expert, row0, rows_valid)) return;

  const int lane = tid & 63, wave = tid >> 6;
  const int wr = wave >> 1, wc = wave & 1;
  const int i0 = bx * 64;
  const unsigned short* W = w1t + (size_t)expert * 2816 * HIDDEN;

  const int q0 = wave * 2, q1 = wave * 2 + 1;
  const int sr0 = q0 * 16 + (lane >> 2), sr1 = q1 * 16 + (lane >> 2);
  const int sb = wave * 16 + (lane >> 2);
  // T2 pre-swizzled source chunk (write side of the LDS swizzle).
  const int sk = (((lane & 3) ^ ((lane >> 3) & 3))) * 8;
  const size_t arow0 = (size_t)min(row0 + sr0, TOKENS - 1);
  const size_t arow1 = (size_t)min(row0 + sr1, TOKENS - 1);
  const unsigned short* pa0 = xb + arow0 * HIDDEN + sk;
  const unsigned short* pa1 = xb + arow1 * HIDDEN + sk;
  const unsigned short* pg = W + (size_t)(i0 + sb) * HIDDEN + sk;
  const unsigned short* pu = W + (size_t)(INTER + i0 + sb) * HIDDEN + sk;

  f32x4 accg[4][2] = {};
  f32x4 accu[4][2] = {};
  const int fr = lane & 15, fq = (lane >> 4) * 8;
  const int fqs = fq ^ (((fr >> 1) & 3) << 3);   // T2 read-side (lane const)

  // prologue: stage K-tile 0 into buffer 0
  GLOAD_LDS16(pa0, AS(0) + q0 * 512);
  GLOAD_LDS16(pa1, AS(0) + q1 * 512);
  GLOAD_LDS16(pg, BG(0) + wave * 512);
  GLOAD_LDS16(pu, BU(0) + wave * 512);
  pa0 += 32; pa1 += 32; pg += 32; pu += 32;
  __syncthreads();

  const int NT = HIDDEN / 32;   // 32
  for (int it = 0; it < NT; ++it) {
    const int cur = it & 1, nxt = cur ^ 1;
    if (it + 1 < NT) {
      GLOAD_LDS16(pa0, AS(nxt) + q0 * 512);
      GLOAD_LDS16(pa1, AS(nxt) + q1 * 512);
      GLOAD_LDS16(pg, BG(nxt) + wave * 512);
      GLOAD_LDS16(pu, BU(nxt) + wave * 512);
      pa0 += 32; pa1 += 32; pg += 32; pu += 32;
    }

    bf16x8 a[4], bg[2], bu[2];
#pragma unroll
    for (int mi = 0; mi < 4; mi++)
      a[mi] = *(const bf16x8*)&AS(cur)[(wr * 64 + mi * 16 + fr) * 32 + fqs];
#pragma unroll
    for (int ni = 0; ni < 2; ni++) {
      bg[ni] = *(const bf16x8*)&BG(cur)[(wc * 32 + ni * 16 + fr) * 32 + fqs];
      bu[ni] = *(const bf16x8*)&BU(cur)[(wc * 32 + ni * 16 + fr) * 32 + fqs];
    }
#pragma unroll
    for (int mi = 0; mi < 4; mi++)
#pragma unroll
      for (int ni = 0; ni < 2; ni++) {
        accg[mi][ni] =
            __builtin_amdgcn_mfma_f32_16x16x32_bf16(a[mi], bg[ni], accg[mi][ni], 0, 0, 0);
        accu[mi][ni] =
            __builtin_amdgcn_mfma_f32_16x16x32_bf16(a[mi], bu[ni], accu[mi][ni], 0, 0, 0);
      }

    __syncthreads();
  }

  // C/D layout: col=lane&15, row=(lane>>4)*4+r  [measured m89/m91]
#pragma unroll
  for (int mi = 0; mi < 4; mi++)
#pragma unroll
    for (int r = 0; r < 4; r++) {
      const int row_local = wr * 64 + mi * 16 + ((lane >> 4) * 4) + r;
      if (row_local < rows_valid && row0 + row_local < TOKENS) {
        const size_t rowoff = (size_t)(row0 + row_local) * INTER;
#pragma unroll
        for (int ni = 0; ni < 2; ni++) {
          const int col = i0 + wc * 32 + ni * 16 + fr;
          const float g = accg[mi][ni][r];
          const float u = accu[mi][ni][r];
          const float sg = g / (1.0f + __expf(-g));
          h[rowoff + col] = f2bf(sg * u);
        }
      }
    }
#undef AS
#undef BG
#undef BU
}

// ---------- GEMM2: out = h @ w2[e], tile 128x128 (R11 proven) ----------
__global__ __launch_bounds__(256, 2) void moe_gemm2(
    const unsigned short* __restrict__ h, const unsigned short* __restrict__ w2t,
    const int* __restrict__ tpe_raw, void* __restrict__ out,
    const float* __restrict__ xf) {
  __shared__ unsigned short As[2][128 * 32];   // 16 KB
  __shared__ unsigned short Bs[2][128 * 32];   // 16 KB

  // T1: bijective XCD chunk swizzle. nwg = 576 = 8*72 (9 y-rows per XCD).
  const int lin = blockIdx.y * 8 + blockIdx.x;
  const int swz = (lin & 7) * 72 + (lin >> 3);
  const int by = swz >> 3, bx = swz & 7;

  int expert, row0, rows_valid;
  if (!expert_map(tpe_raw, by, expert, row0, rows_valid)) return;
  const int f32out = detect_f32(xf, threadIdx.x & 63);

  const int tid = threadIdx.x;
  const int lane = tid & 63, wave = tid >> 6;
  const int wr = wave >> 1, wc = wave & 1;
  const int n0 = bx * 128;
  const unsigned short* W = w2t + (size_t)expert * INTER * HIDDEN;

  const int q0 = wave * 2, q1 = wave * 2 + 1;
  const int sr0 = q0 * 16 + (lane >> 2), sr1 = q1 * 16 + (lane >> 2);
  const int sk = (((lane & 3) ^ ((lane >> 3) & 3))) * 8;   // T2 source swizzle
  const size_t arow0 = (size_t)min(row0 + sr0, TOKENS - 1);
  const size_t arow1 = (size_t)min(row0 + sr1, TOKENS - 1);
  const unsigned short* pa0 = h + arow0 * INTER + sk;
  const unsigned short* pa1 = h + arow1 * INTER + sk;
  const unsigned short* pb0 = W + (size_t)(n0 + sr0) * INTER + sk;
  const unsigned short* pb1 = W + (size_t)(n0 + sr1) * INTER + sk;

  f32x4 acc[4][4] = {};
  const int fr = lane & 15, fq = (lane >> 4) * 8;
  const int fqs = fq ^ (((fr >> 1) & 3) << 3);             // T2 read swizzle

  // prologue: stage K-tile 0
  GLOAD_LDS16(pa0, &As[0][q0 * 512]);
  GLOAD_LDS16(pa1, &As[0][q1 * 512]);
  GLOAD_LDS16(pb0, &Bs[0][q0 * 512]);
  GLOAD_LDS16(pb1, &Bs[0][q1 * 512]);
  pa0 += 32; pa1 += 32; pb0 += 32; pb1 += 32;
  __syncthreads();

  const int NT = INTER / 32;   // 44
  for (int it = 0; it < NT; ++it) {
    const int cur = it & 1, nxt = cur ^ 1;
    if (it + 1 < NT) {
      GLOAD_LDS16(pa0, &As[nxt][q0 * 512]);
      GLOAD_LDS16(pa1, &As[nxt][q1 * 512]);
      GLOAD_LDS16(pb0, &Bs[nxt][q0 * 512]);
      GLOAD_LDS16(pb1, &Bs[nxt][q1 * 512]);
      pa0 += 32; pa1 += 32; pb0 += 32; pb1 += 32;
    }

    bf16x8 a[4], bb[4];
#pragma unroll
    for (int mi = 0; mi < 4; mi++)
      a[mi] = *(const bf16x8*)&As[cur][(wr * 64 + mi * 16 + fr) * 32 + fqs];
#pragma unroll
    for (int ni = 0; ni < 4; ni++)
      bb[ni] = *(const bf16x8*)&Bs[cur][(wc * 64 + ni * 16 + fr) * 32 + fqs];
#pragma unroll
    for (int mi = 0; mi < 4; mi++)
#pragma unroll
      for (int ni = 0; ni < 4; ni++)
        acc[mi][ni] =
            __builtin_amdgcn_mfma_f32_16x16x32_bf16(a[mi], bb[ni], acc[mi][ni], 0, 0, 0);

    __syncthreads();
  }

#pragma unroll
  for (int mi = 0; mi < 4; mi++)
#pragma unroll
    for (int r = 0; r < 4; r++) {
      const int row_local = wr * 64 + mi * 16 + ((lane >> 4) * 4) + r;
      if (row_local < rows_valid && row0 + row_local < TOKENS) {
        const size_t rowoff = (size_t)(row0 + row_local) * HIDDEN;
#pragma unroll
        for (int ni = 0; ni < 4; ni++) {
          const int col = n0 + wc * 64 + ni * 16 + fr;
          if (f32out)
            ((float*)out)[rowoff + col] = acc[mi][ni][r];
          else
            ((unsigned short*)out)[rowoff + col] = f2bf(acc[mi][ni][r]);
        }
      }
    }
}

extern "C" void kernel_launch(void* const* d_in, const int* in_sizes, int n_in,
                              void* d_out, int out_size, void* d_ws, size_t ws_size,
                              hipStream_t stream) {
  const void* x = d_in[0];
  const void* w1w3 = d_in[1];
  const void* w2 = d_in[2];
  const int* tpe = (const int*)d_in[3];
  const float* xf = (const float*)d_in[0];

  // ws: xb[8192][1024] | w1t[8][2816][1024] | w2t[8][1024][1408] | h[8192][1408]
  const size_t XB_BYTES = (size_t)TOKENS * HIDDEN * 2;         // 16,777,216
  const size_t W1T_BYTES = (size_t)NEXP * 2816 * HIDDEN * 2;   // 46,137,344
  const size_t W2T_BYTES = (size_t)NEXP * INTER * HIDDEN * 2;  // 23,068,672
  char* ws = (char*)d_ws;
  unsigned short* xb = (unsigned short*)ws;
  unsigned short* w1t = (unsigned short*)(ws + XB_BYTES);
  unsigned short* w2t = (unsigned short*)(ws + XB_BYTES + W1T_BYTES);
  unsigned short* h = (unsigned short*)(ws + XB_BYTES + W1T_BYTES + W2T_BYTES);

  prepare<<<1920, 256, 0, stream>>>(xf, x, w1w3, xb, w1t);
  // gemm1 grid: y in [0,72) = GEMM tiles; y in [72,104) = w2-transpose blocks
  moe_gemm1<<<dim3(22, 104), 256, 0, stream>>>(xb, w1t, tpe, h, w2, w2t, xf);
  moe_gemm2<<<dim3(8, 72), 256, 0, stream>>>(h, w2t, tpe, d_out, xf);
}